// Round 6
// baseline (1317.637 us; speedup 1.0000x reference)
//
#include <hip/hip_runtime.h>

typedef _Float16 f16;
typedef __attribute__((ext_vector_type(4)))  _Float16 f16x4;
typedef __attribute__((ext_vector_type(8)))  _Float16 f16x8;
typedef __attribute__((ext_vector_type(16))) float    f32x16;

#define WT_L (8*256*256)   // halves per middle layer (d=1..8)

__device__ __forceinline__ float fexp2(float x) {
#if __has_builtin(__builtin_amdgcn_exp2f)
    return __builtin_amdgcn_exp2f(x);
#else
    return exp2f(x);
#endif
}

__device__ __forceinline__ float fast_tanh(float v) {
    float a = __builtin_fabsf(v);
    float e = fexp2(a * -2.8853900817779268f);
    float r = (1.0f - e) * __builtin_amdgcn_rcpf(1.0f + e);
    return __builtin_copysignf(r, v);
}

// ---------------- prep: all weights in one launch ----------------
// blocks 0..1535: mid layers (L=bi>>8, o=bi&255)  w[i][o][d] -> wt[d-1][o][i] f16 + bias
// blocks 1536..1562: w0  -> w0t[(i*9+d)*256+o] fp32
// blocks 1563..1571: w7  -> w7p[ch*12+d] fp32
__global__ void prep_all(const float* __restrict__ w0, const float* __restrict__ w1,
                         const float* __restrict__ w2, const float* __restrict__ w3,
                         const float* __restrict__ w4, const float* __restrict__ w5,
                         const float* __restrict__ w6, const float* __restrict__ w7,
                         f16* __restrict__ wt, float* __restrict__ biasp,
                         float* __restrict__ w0t, float* __restrict__ w7p)
{
    __shared__ float red[256];
    const int bi = blockIdx.x, t = threadIdx.x;
    if (bi < 1536) {
        const int L = bi >> 8, o = bi & 255, i = t;
        const float* w;
        switch (L) { case 0: w = w1; break; case 1: w = w2; break; case 2: w = w3; break;
                     case 3: w = w4; break; case 4: w = w5; break; default: w = w6; }
        float v[9];
#pragma unroll
        for (int d = 0; d < 9; d++) v[d] = w[(i*256 + o)*9 + d];
#pragma unroll
        for (int d = 1; d < 9; d++) wt[L*WT_L + ((d-1)*256 + o)*256 + i] = (f16)v[d];
        red[i] = v[0];
        __syncthreads();
#pragma unroll
        for (int s = 128; s > 0; s >>= 1) {
            if (i < s) red[i] += red[i + s];
            __syncthreads();
        }
        if (i == 0) biasp[L*256 + o] = red[0];
    } else if (bi < 1563) {
        int id = (bi - 1536)*256 + t;      // < 6912
        int i = id / 2304, rem = id % 2304;
        int o = rem / 9, d = rem % 9;
        w0t[(i*9 + d)*256 + o] = w0[id];
    } else {
        int id = (bi - 1563)*256 + t;      // < 2304
        int ch = id / 9, d = id % 9;
        w7p[ch*12 + d] = w7[id];
    }
}

// ---------------- the proven R5 GEMM core as a device function ----------------
// xs: [pt][ch] f16, XOR-swizzled 16B units. One full 256->256 ChebyKAN layer,
// M=128 (whole block), wave tile mt4 x nt2, register Chebyshev A-recurrence,
// 4-slot B prefetch ring. Ends with tanh writeback into xs + barrier.
__device__ __forceinline__ void gemm_layer(f16* __restrict__ xs,
                                           const f16* __restrict__ wl,
                                           const float* __restrict__ biasL,
                                           int l31, int half, int nb)
{
    f32x16 acc[4][2];
    const f16x8 ones = {(f16)1.f,(f16)1.f,(f16)1.f,(f16)1.f,(f16)1.f,(f16)1.f,(f16)1.f,(f16)1.f};

    const f16* wbase = wl + half*8 + (nb + l31)*256;   // + ck*16 + (d-1)*65536 (+8192 for nt1)
    float b0 = biasL[nb + l31];
    float b1 = biasL[nb + 32 + l31];
#pragma unroll
    for (int mt = 0; mt < 4; mt++)
#pragma unroll
        for (int r = 0; r < 16; r++) { acc[mt][0][r] = b0; acc[mt][1][r] = b1; }

    f16x8 xv[4], Bb[4][2];
#pragma unroll
    for (int mt = 0; mt < 4; mt++) {
        int m = mt*32 + l31;
        int unit = half ^ (m & 7);
        xv[mt] = *(const f16x8*)(xs + m*256 + unit*8);
    }
#pragma unroll
    for (int j = 0; j < 4; j++) {
        Bb[j][0] = *(const f16x8*)(wbase + j*65536);
        Bb[j][1] = *(const f16x8*)(wbase + j*65536 + 8192);
    }

    f16x8 x2[4], t1[4], t0[4];
#pragma unroll 1
    for (int ck = 0; ck < 16; ck++) {
        const int ckn = (ck < 15) ? ck + 1 : 15;
#pragma unroll
        for (int mt = 0; mt < 4; mt++) {
            t1[mt] = xv[mt];
            x2[mt] = xv[mt] + xv[mt];
            t0[mt] = ones;
        }
#pragma unroll
        for (int mt = 0; mt < 4; mt++) {
            int m = mt*32 + l31;
            int unit = (ckn*2 + half) ^ (m & 7);
            xv[mt] = *(const f16x8*)(xs + m*256 + unit*8);
        }
#pragma unroll
        for (int j = 0; j < 8; j++) {
            const int ck2 = (j < 4) ? ck : ckn;
            const int j2  = (j < 4) ? (j + 4) : (j - 4);
            f16x8 pb0 = *(const f16x8*)(wbase + ck2*16 + j2*65536);
            f16x8 pb1 = *(const f16x8*)(wbase + ck2*16 + j2*65536 + 8192);
#pragma unroll
            for (int mt = 0; mt < 4; mt++) {
                acc[mt][0] = __builtin_amdgcn_mfma_f32_32x32x16_f16(t1[mt], Bb[j&3][0], acc[mt][0], 0, 0, 0);
                acc[mt][1] = __builtin_amdgcn_mfma_f32_32x32x16_f16(t1[mt], Bb[j&3][1], acc[mt][1], 0, 0, 0);
            }
            if (j < 7) {
#pragma unroll
                for (int mt = 0; mt < 4; mt++) {
                    f16x8 tn = x2[mt]*t1[mt] - t0[mt];
                    t0[mt] = t1[mt];
                    t1[mt] = tn;
                }
            }
            Bb[j&3][0] = pb0;
            Bb[j&3][1] = pb1;
        }
    }
    __syncthreads();   // all xs reads done

#pragma unroll
    for (int mt = 0; mt < 4; mt++) {
#pragma unroll
        for (int nt = 0; nt < 2; nt++) {
            int ch = nb + nt*32 + l31;
            int cu = ch >> 3, ce = ch & 7;
#pragma unroll
            for (int r = 0; r < 16; r++) {
                int p = mt*32 + (r & 3) + 8*(r >> 2) + 4*half;
                int unit = cu ^ (p & 7);
                xs[p*256 + unit*8 + ce] = (f16)fast_tanh(acc[mt][nt][r]);
            }
        }
    }
    __syncthreads();
}

// ---------------- stage helpers: xg layout [tile][cu(32)][pt(128)][e(8)] ----------------
__device__ __forceinline__ void stage_in(f16* __restrict__ xs, const f16* __restrict__ xg,
                                         size_t tile_off, int t)
{
#pragma unroll
    for (int i = 0; i < 16; i++) {
        int idx = i*256 + t;               // 0..4095
        int cu = idx >> 7, pt = idx & 127;
        f16x8 v = *(const f16x8*)(xg + tile_off + (size_t)idx*8);
        *(f16x8*)(xs + pt*256 + ((cu ^ (pt & 7))*8)) = v;
    }
    __syncthreads();
}

__device__ __forceinline__ void stage_out(const f16* __restrict__ xs, f16* __restrict__ xg,
                                          size_t tile_off, int t)
{
#pragma unroll
    for (int i = 0; i < 16; i++) {
        int idx = i*256 + t;
        int cu = idx >> 7, pt = idx & 127;
        f16x8 v = *(const f16x8*)(xs + pt*256 + ((cu ^ (pt & 7))*8));
        *(f16x8*)(xg + tile_off + (size_t)idx*8) = v;
    }
}

// ---------------- kA: [layer0 from points] + GEMM L1 + GEMM L2 -> xg ----------------
__global__ __launch_bounds__(256, 2)
void kA(const float* __restrict__ nonm, const float* __restrict__ mnf,
        const float* __restrict__ w0t, const f16* __restrict__ wt,
        const float* __restrict__ bias, f16* __restrict__ xg)
{
    __shared__ __align__(16) f16 xs[128*256];
    const int t = threadIdx.x, b = blockIdx.x;
    const int lane = t & 63, w = t >> 6;
    const int l31 = lane & 31, half = lane >> 5, nb = w * 64;

    // ---- layer 0: 3 -> 256, fp32 VALU, 2 threads per point ----
    {
        const int pt = t >> 1;
        const int oh = (t & 1) * 128;
        const int pid = b*128 + pt;                 // 0..131071; <65536 = mnfld
        const float* src = (pid < 65536) ? mnf : nonm;
        const int sp = (pid < 65536) ? pid : pid - 65536;
        float c0 = src[sp*3 + 0];
        float c1 = src[sp*3 + 1];
        float c2 = src[sp*3 + 2];
        float xx[3] = {fast_tanh(c0), fast_tanh(c1), fast_tanh(c2)};
        float bas[27];
#pragma unroll
        for (int i = 0; i < 3; i++) {
            float t0 = 1.0f, t1 = xx[i];
            bas[i*9+0] = t0; bas[i*9+1] = t1;
            float x2 = xx[i] + xx[i];
#pragma unroll
            for (int d = 2; d < 9; d++) {
                float t2 = x2*t1 - t0;
                bas[i*9+d] = t2; t0 = t1; t1 = t2;
            }
        }
#pragma unroll 1
        for (int q = 0; q < 32; q++) {
            int o = oh + q*4;
            float4 a = {0.f, 0.f, 0.f, 0.f};
#pragma unroll
            for (int k = 0; k < 27; k++) {
                float4 wv = *(const float4*)(w0t + k*256 + o);
                a.x = fmaf(bas[k], wv.x, a.x);
                a.y = fmaf(bas[k], wv.y, a.y);
                a.z = fmaf(bas[k], wv.z, a.z);
                a.w = fmaf(bas[k], wv.w, a.w);
            }
            f16x4 hv = {(f16)fast_tanh(a.x), (f16)fast_tanh(a.y),
                        (f16)fast_tanh(a.z), (f16)fast_tanh(a.w)};
            int unit = (o >> 3) ^ (pt & 7);
            *(f16x4*)(xs + pt*256 + unit*8 + (o & 7)) = hv;
        }
    }
    __syncthreads();

    gemm_layer(xs, wt + 0*WT_L, bias + 0*256, l31, half, nb);
    gemm_layer(xs, wt + 1*WT_L, bias + 1*256, l31, half, nb);

    stage_out(xs, xg, (size_t)b * 32768, t);
}

// ---------------- kB: GEMM L3 + GEMM L4 (xg in-place) ----------------
__global__ __launch_bounds__(256, 2)
void kB(const f16* __restrict__ wt, const float* __restrict__ bias, f16* __restrict__ xg)
{
    __shared__ __align__(16) f16 xs[128*256];
    const int t = threadIdx.x, b = blockIdx.x;
    const int lane = t & 63, w = t >> 6;
    const int l31 = lane & 31, half = lane >> 5, nb = w * 64;
    const size_t tile_off = (size_t)b * 32768;

    stage_in(xs, xg, tile_off, t);
    gemm_layer(xs, wt + 2*WT_L, bias + 2*256, l31, half, nb);
    gemm_layer(xs, wt + 3*WT_L, bias + 3*256, l31, half, nb);
    stage_out(xs, xg, tile_off, t);
}

// ---------------- kC: GEMM L5 + GEMM L6 + [layer 7 -> out] ----------------
__global__ __launch_bounds__(256, 2)
void kC(const f16* __restrict__ wt, const float* __restrict__ bias,
        const float* __restrict__ w7p, f16* __restrict__ xg, float* __restrict__ out)
{
    __shared__ __align__(16) f16 xs[128*256];
    const int t = threadIdx.x, b = blockIdx.x;
    const int lane = t & 63, w = t >> 6;
    const int l31 = lane & 31, half = lane >> 5, nb = w * 64;
    const size_t tile_off = (size_t)b * 32768;

    stage_in(xs, xg, tile_off, t);
    gemm_layer(xs, wt + 4*WT_L, bias + 4*256, l31, half, nb);
    gemm_layer(xs, wt + 5*WT_L, bias + 5*256, l31, half, nb);

    // ---- layer 7: 256 -> 1, fp32 VALU, 2 threads per point ----
    {
        const int pt = t & 127;
        const int seg = t >> 7;
        float s = 0.0f;
#pragma unroll 1
        for (int q = 0; q < 16; q++) {
            int u = seg*16 + q;
            int unit = u ^ (pt & 7);
            f16x8 xv = *(const f16x8*)(xs + pt*256 + unit*8);
#pragma unroll
            for (int e = 0; e < 8; e++) {
                int ch = u*8 + e;
                const float* wr = w7p + ch*12;
                float x = (float)xv[e];
                float4 wa = *(const float4*)(wr);
                float4 wb = *(const float4*)(wr + 4);
                float wc = wr[8];
                float x2 = x + x;
                float t0 = 1.0f, t1v = x;
                s = fmaf(wa.x, t0, s);
                s = fmaf(wa.y, t1v, s);
                float t2 = x2*t1v - t0;  s = fmaf(wa.z, t2, s);
                float t3 = x2*t2 - t1v;  s = fmaf(wa.w, t3, s);
                float t4 = x2*t3 - t2;   s = fmaf(wb.x, t4, s);
                float t5 = x2*t4 - t3;   s = fmaf(wb.y, t5, s);
                float t6 = x2*t5 - t4;   s = fmaf(wb.z, t6, s);
                float t7 = x2*t6 - t5;   s = fmaf(wb.w, t7, s);
                float t8 = x2*t7 - t6;   s = fmaf(wc,  t8, s);
            }
        }
        __syncthreads();          // xs reads done; reuse as fp32 scratch
        float* red = (float*)xs;
        red[seg*128 + pt] = s;
        __syncthreads();
        if (t < 128) out[b*128 + t] = red[t] + red[128 + t];
    }
}

// ---------------- launch ----------------
extern "C" void kernel_launch(void* const* d_in, const int* in_sizes, int n_in,
                              void* d_out, int out_size, void* d_ws, size_t ws_size,
                              hipStream_t stream) {
    const float* nonm = (const float*)d_in[0];
    const float* mnf  = (const float*)d_in[1];

    char* ws = (char*)d_ws;
    f16*   wtp   = (f16*)ws;                                       // 6,291,456 B
    float* biasp = (float*)(ws + 6*WT_L*2);                        // 6144 B
    float* w0tp  = (float*)(ws + 6*WT_L*2 + 6144);                 // 27648 B
    float* w7pp  = (float*)(ws + 6*WT_L*2 + 6144 + 27648);         // 12288 B
    f16*   xg    = (f16*)(ws + 6*WT_L*2 + 6144 + 27648 + 12288);   // 67,108,864 B

    prep_all<<<1572, 256, 0, stream>>>((const float*)d_in[2], (const float*)d_in[3],
                                       (const float*)d_in[4], (const float*)d_in[5],
                                       (const float*)d_in[6], (const float*)d_in[7],
                                       (const float*)d_in[8], (const float*)d_in[9],
                                       wtp, biasp, w0tp, w7pp);

    kA<<<1024, 256, 0, stream>>>(nonm, mnf, w0tp, wtp, biasp, xg);
    kB<<<1024, 256, 0, stream>>>(wtp, biasp, xg);
    kC<<<1024, 256, 0, stream>>>(wtp, biasp, w7pp, xg, (float*)d_out);
}

// Round 7
// 1002.838 us; speedup vs baseline: 1.3139x; 1.3139x over previous
//
#include <hip/hip_runtime.h>

typedef _Float16 f16;
typedef __attribute__((ext_vector_type(4)))  _Float16 f16x4;
typedef __attribute__((ext_vector_type(8)))  _Float16 f16x8;
typedef __attribute__((ext_vector_type(16))) float    f32x16;

#define WT_L (8*256*256)   // halves per middle layer (d=1..8)

__device__ __forceinline__ float fexp2(float x) {
#if __has_builtin(__builtin_amdgcn_exp2f)
    return __builtin_amdgcn_exp2f(x);
#else
    return exp2f(x);
#endif
}

__device__ __forceinline__ float fast_tanh(float v) {
    float a = __builtin_fabsf(v);
    float e = fexp2(a * -2.8853900817779268f);
    float r = (1.0f - e) * __builtin_amdgcn_rcpf(1.0f + e);
    return __builtin_copysignf(r, v);
}

// ---------------- prep: all weights in one launch ----------------
// mid layers -> wave-contiguous B layout:
//   wt2 half-index = ((d-1)*16 + ck)*4096 + w*1024 + nt*512 + (half*32 + l31)*8 + e
//   where i = ck*16 + (half*8 + e)  (input ch), o = w*64 + nt*32 + l31  (output ch)
// blocks 0..1535: mid layers (L=bi>>8, o=bi&255)
// blocks 1536..1562: w0 -> w0t[(i*9+d)*256+o] fp32
// blocks 1563..1571: w7 -> w7p[ch*12+d] fp32
__global__ void prep_all(const float* __restrict__ w0, const float* __restrict__ w1,
                         const float* __restrict__ w2, const float* __restrict__ w3,
                         const float* __restrict__ w4, const float* __restrict__ w5,
                         const float* __restrict__ w6, const float* __restrict__ w7,
                         f16* __restrict__ wt, float* __restrict__ biasp,
                         float* __restrict__ w0t, float* __restrict__ w7p)
{
    __shared__ float red[256];
    const int bi = blockIdx.x, t = threadIdx.x;
    if (bi < 1536) {
        const int L = bi >> 8, o = bi & 255, i = t;
        const float* w;
        switch (L) { case 0: w = w1; break; case 1: w = w2; break; case 2: w = w3; break;
                     case 3: w = w4; break; case 4: w = w5; break; default: w = w6; }
        float v[9];
#pragma unroll
        for (int d = 0; d < 9; d++) v[d] = w[(i*256 + o)*9 + d];
        const int ck = i >> 4, k = i & 15;
        const int wv4 = o >> 6, nt = (o >> 5) & 1, l31 = o & 31;
        const int lane = (k >> 3)*32 + l31, e = k & 7;
        const int base = ck*4096 + wv4*1024 + nt*512 + lane*8 + e;
#pragma unroll
        for (int d = 1; d < 9; d++)
            wt[L*WT_L + (d-1)*16*4096 + base] = (f16)v[d];
        red[i] = v[0];
        __syncthreads();
#pragma unroll
        for (int s = 128; s > 0; s >>= 1) {
            if (i < s) red[i] += red[i + s];
            __syncthreads();
        }
        if (i == 0) biasp[L*256 + o] = red[0];
    } else if (bi < 1563) {
        int id = (bi - 1536)*256 + t;      // < 6912
        int i = id / 2304, rem = id % 2304;
        int o = rem / 9, d = rem % 9;
        w0t[(i*9 + d)*256 + o] = w0[id];
    } else {
        int id = (bi - 1563)*256 + t;      // < 2304
        int ch = id / 9, d = id % 9;
        w7p[ch*12 + d] = w7[id];
    }
}

// ---------------- layer 0: points -> x1 = tanh(h1), f16 [pt][ch] global ----------------
__global__ void k0(const float* __restrict__ nonm, const float* __restrict__ mnf,
                   const float* __restrict__ w0t, f16* __restrict__ xg) {
    const int t = threadIdx.x, b = blockIdx.x;
    const int pt = t & 63;
    const int oh = (t >> 6) * 64;
    const int pid = b*64 + pt;                 // 0..131071; 0..65535 = mnfld
    const float* src = (pid < 65536) ? mnf : nonm;
    const int sp = (pid < 65536) ? pid : pid - 65536;
    float c0 = src[sp*3 + 0];
    float c1 = src[sp*3 + 1];
    float c2 = src[sp*3 + 2];
    float xx[3] = {fast_tanh(c0), fast_tanh(c1), fast_tanh(c2)};
    float bas[27];
#pragma unroll
    for (int i = 0; i < 3; i++) {
        float t0 = 1.0f, t1 = xx[i];
        bas[i*9+0] = t0; bas[i*9+1] = t1;
        float x2 = xx[i] + xx[i];
#pragma unroll
        for (int d = 2; d < 9; d++) {
            float t2 = x2*t1 - t0;
            bas[i*9+d] = t2; t0 = t1; t1 = t2;
        }
    }
#pragma unroll 1
    for (int q = 0; q < 16; q++) {
        int o = oh + q*4;
        float4 a = {0.f, 0.f, 0.f, 0.f};
#pragma unroll
        for (int k = 0; k < 27; k++) {
            float4 wv = *(const float4*)(w0t + k*256 + o);
            a.x = fmaf(bas[k], wv.x, a.x);
            a.y = fmaf(bas[k], wv.y, a.y);
            a.z = fmaf(bas[k], wv.z, a.z);
            a.w = fmaf(bas[k], wv.w, a.w);
        }
        f16x4 hv = {(f16)fast_tanh(a.x), (f16)fast_tanh(a.y),
                    (f16)fast_tanh(a.z), (f16)fast_tanh(a.w)};
        *(f16x4*)(xg + (size_t)pid*256 + o) = hv;
    }
}

// ---------------- middle layer: x -> tanh(GEMM), in-place on xg, one layer per launch ----------------
// 1024 blocks x 256 thr; M=128 pts/tile; wave tile mt4 x nt2; wave-contiguous B layout
__global__ __launch_bounds__(256, 2)
void k_mid(const f16* __restrict__ wl, const float* __restrict__ biasL,
           f16* __restrict__ xg)
{
    __shared__ __align__(16) f16 xs[128*256];   // 64 KB, [pt][ch], XOR-swizzled 16B units

    const int t    = threadIdx.x;
    const int b    = blockIdx.x;
    const int lane = t & 63;
    const int w    = t >> 6;
    const int l31  = lane & 31;
    const int half = lane >> 5;
    const int nb   = w * 64;
    const size_t tile_off = (size_t)b * 128 * 256;

    // ---- stage in: coalesced, swizzle into xs ----
#pragma unroll
    for (int i = 0; i < 16; i++) {
        int idx = i*256 + t;
        int pt = idx >> 5, cu = idx & 31;
        f16x8 v = *(const f16x8*)(xg + tile_off + (size_t)idx*8);
        *(f16x8*)(xs + pt*256 + ((cu ^ (pt & 7))*8)) = v;
    }
    __syncthreads();

    // ---- GEMM: 8 degree-matmuls, register A-recurrence, 4-slot B prefetch ring ----
    f32x16 acc[4][2];
    const f16x8 ones = {(f16)1.f,(f16)1.f,(f16)1.f,(f16)1.f,(f16)1.f,(f16)1.f,(f16)1.f,(f16)1.f};

    // wave-contiguous B: load0 = wbase + (dm*16+ck)*4096, load1 = +512
    const f16* wbase = wl + w*1024 + lane*8;
    float b0 = biasL[nb + l31];
    float b1 = biasL[nb + 32 + l31];
#pragma unroll
    for (int mt = 0; mt < 4; mt++)
#pragma unroll
        for (int r = 0; r < 16; r++) { acc[mt][0][r] = b0; acc[mt][1][r] = b1; }

    f16x8 xv[4], Bb[4][2];
#pragma unroll
    for (int mt = 0; mt < 4; mt++) {
        int m = mt*32 + l31;
        int unit = half ^ (m & 7);
        xv[mt] = *(const f16x8*)(xs + m*256 + unit*8);
    }
#pragma unroll
    for (int j = 0; j < 4; j++) {
        Bb[j][0] = *(const f16x8*)(wbase + j*16*4096);
        Bb[j][1] = *(const f16x8*)(wbase + j*16*4096 + 512);
    }

    f16x8 x2[4], t1[4], t0[4];
#pragma unroll 1
    for (int ck = 0; ck < 16; ck++) {
        const int ckn = (ck < 15) ? ck + 1 : 15;
#pragma unroll
        for (int mt = 0; mt < 4; mt++) {
            t1[mt] = xv[mt];
            x2[mt] = xv[mt] + xv[mt];
            t0[mt] = ones;
        }
#pragma unroll
        for (int mt = 0; mt < 4; mt++) {
            int m = mt*32 + l31;
            int unit = (ckn*2 + half) ^ (m & 7);
            xv[mt] = *(const f16x8*)(xs + m*256 + unit*8);
        }
#pragma unroll
        for (int j = 0; j < 8; j++) {
            const int ck2 = (j < 4) ? ck : ckn;
            const int j2  = (j < 4) ? (j + 4) : (j - 4);
            const int off = (j2*16 + ck2)*4096;
            f16x8 pb0 = *(const f16x8*)(wbase + off);
            f16x8 pb1 = *(const f16x8*)(wbase + off + 512);
#pragma unroll
            for (int mt = 0; mt < 4; mt++) {
                acc[mt][0] = __builtin_amdgcn_mfma_f32_32x32x16_f16(t1[mt], Bb[j&3][0], acc[mt][0], 0, 0, 0);
                acc[mt][1] = __builtin_amdgcn_mfma_f32_32x32x16_f16(t1[mt], Bb[j&3][1], acc[mt][1], 0, 0, 0);
            }
            if (j < 7) {
#pragma unroll
                for (int mt = 0; mt < 4; mt++) {
                    f16x8 tn = x2[mt]*t1[mt] - t0[mt];
                    t0[mt] = t1[mt];
                    t1[mt] = tn;
                }
            }
            Bb[j&3][0] = pb0;
            Bb[j&3][1] = pb1;
        }
    }
    __syncthreads();   // all xs reads done

    // ---- writeback tanh(acc) into xs (swizzled) ----
#pragma unroll
    for (int mt = 0; mt < 4; mt++) {
#pragma unroll
        for (int nt = 0; nt < 2; nt++) {
            int ch = nb + nt*32 + l31;
            int cu = ch >> 3, ce = ch & 7;
#pragma unroll
            for (int r = 0; r < 16; r++) {
                int p = mt*32 + (r & 3) + 8*(r >> 2) + 4*half;
                int unit = cu ^ (p & 7);
                xs[p*256 + unit*8 + ce] = (f16)fast_tanh(acc[mt][nt][r]);
            }
        }
    }
    __syncthreads();

    // ---- stage out: coalesced ----
#pragma unroll
    for (int i = 0; i < 16; i++) {
        int idx = i*256 + t;
        int pt = idx >> 5, cu = idx & 31;
        f16x8 v = *(const f16x8*)(xs + pt*256 + ((cu ^ (pt & 7))*8));
        *(f16x8*)(xg + tile_off + (size_t)idx*8) = v;
    }
}

// ---------------- layer 7: 256 -> 1 ----------------
__global__ void k7(const f16* __restrict__ xg, const float* __restrict__ w7p,
                   float* __restrict__ out) {
    __shared__ float w7s[256*12];   // 12 KB
    const int t = threadIdx.x, b = blockIdx.x;
#pragma unroll
    for (int i = 0; i < 12; i++) w7s[i*256 + t] = w7p[i*256 + t];
    __syncthreads();
    const int pid = b*256 + t;
    const f16* row = xg + (size_t)pid*256;
    float s = 0.0f;
#pragma unroll 1
    for (int cu = 0; cu < 32; cu++) {
        f16x8 xv = *(const f16x8*)(row + cu*8);
#pragma unroll
        for (int e = 0; e < 8; e++) {
            int ch = cu*8 + e;
            const float* wr = w7s + ch*12;
            float x = (float)xv[e];
            float x2 = x + x;
            float t0 = 1.0f, t1v = x;
            s = fmaf(wr[0], t0, s);
            s = fmaf(wr[1], t1v, s);
            float t2 = x2*t1v - t0;  s = fmaf(wr[2], t2, s);
            float t3 = x2*t2 - t1v;  s = fmaf(wr[3], t3, s);
            float t4 = x2*t3 - t2;   s = fmaf(wr[4], t4, s);
            float t5 = x2*t4 - t3;   s = fmaf(wr[5], t5, s);
            float t6 = x2*t5 - t4;   s = fmaf(wr[6], t6, s);
            float t7 = x2*t6 - t5;   s = fmaf(wr[7], t7, s);
            float t8 = x2*t7 - t6;   s = fmaf(wr[8], t8, s);
        }
    }
    out[pid] = s;
}

// ---------------- launch ----------------
extern "C" void kernel_launch(void* const* d_in, const int* in_sizes, int n_in,
                              void* d_out, int out_size, void* d_ws, size_t ws_size,
                              hipStream_t stream) {
    const float* nonm = (const float*)d_in[0];
    const float* mnf  = (const float*)d_in[1];

    char* ws = (char*)d_ws;
    f16*   wtp   = (f16*)ws;                                       // 6,291,456 B
    float* biasp = (float*)(ws + 6*WT_L*2);                        // 6144 B
    float* w0tp  = (float*)(ws + 6*WT_L*2 + 6144);                 // 27648 B
    float* w7pp  = (float*)(ws + 6*WT_L*2 + 6144 + 27648);         // 12288 B
    f16*   xg    = (f16*)(ws + 6*WT_L*2 + 6144 + 27648 + 12288);   // 67,108,864 B

    prep_all<<<1572, 256, 0, stream>>>((const float*)d_in[2], (const float*)d_in[3],
                                       (const float*)d_in[4], (const float*)d_in[5],
                                       (const float*)d_in[6], (const float*)d_in[7],
                                       (const float*)d_in[8], (const float*)d_in[9],
                                       wtp, biasp, w0tp, w7pp);

    k0<<<2048, 256, 0, stream>>>(nonm, mnf, w0tp, xg);
    for (int L = 0; L < 6; L++)
        k_mid<<<1024, 256, 0, stream>>>(wtp + L*WT_L, biasp + L*256, xg);
    k7<<<512, 256, 0, stream>>>(xg, w7pp, (float*)d_out);
}